// Round 11
// baseline (265.883 us; speedup 1.0000x reference)
//
#include <hip/hip_runtime.h>
#include <hip/hip_cooperative_groups.h>
#include <math.h>

namespace cg = cooperative_groups;

// PointLaplacianLoss — round 11: single cooperative mega-kernel.
//
// Rounds 5-10 evidence: four different phase1 bodies all give 121-124 us e2e;
// the real VALU work is ~3 us. The cost is the 6-dispatch serialized pipeline
// (drain/ramp per kernel, 2-block scan, uneven phase1 tails). This round
// collapses everything into ONE hipLaunchCooperativeKernel with grid.sync()
// between stages:
//   A zero hist/out/nfail   B pack+bin(atomics)   C two-level scan (256 blk)
//   D scatter               E phase1 (per-lane 3^3/5^3, z-slab batched bounds)
//   F phase2 (wave-per-failed-query brute force)
// Grid 256x512 = 1 block/CU (trivially co-resident). Fallback (small ws):
// round-2 brute force, unchanged.

constexpr int NPTS  = 8192;
constexpr int NB    = 2;
constexpr int KNN   = 10;
constexpr int QPB   = 64;
constexpr int WPB   = 8;
constexpr int BLOCK = 512;
constexpr int GRID  = 256;
constexpr int MASK13 = 0xFFFFE000;

constexpr int   G    = 32;
constexpr int   NC   = G * G * G;
constexpr float BMIN = -5.5f;
constexpr float BW   = 11.0f;
constexpr float H    = BW / G;          // 0.34375
constexpr float INVH = (float)G / BW;

// ---------------- selection helpers ----------------
__device__ __forceinline__ void ins1(int l[KNN], int x) {
#pragma unroll
    for (int k = KNN - 1; k > 0; --k) l[k] = min(l[k], max(l[k - 1], x));
    l[0] = min(l[0], x);
}
__device__ __forceinline__ void ins2(int l[KNN], int a, int b) {
    const int b0 = min(a, b), b1 = max(a, b);
#pragma unroll
    for (int k = KNN - 1; k >= 2; --k)
        l[k] = min(l[k], min(max(l[k - 1], b0), max(l[k - 2], b1)));
    l[1] = min(l[1], min(max(l[0], b0), b1));
    l[0] = min(l[0], b0);
}
template<int S>
__device__ __forceinline__ void ins2s(int l[KNN], int a, int b) {
    const int b0 = min(a, b), b1 = max(a, b);
#pragma unroll
    for (int k = KNN - 1; k >= S + 2; --k)
        l[k] = min(l[k], min(max(l[k - 1], b0), max(l[k - 2], b1)));
    l[S + 1] = min(l[S + 1], min(max(l[S], b0), b1));
    l[S] = min(l[S], b0);
}
__device__ __forceinline__ void merge_sorted(int l[KNN], const int p[KNN]) {
    ins2s<0>(l, p[0], p[1]);
    ins2s<2>(l, p[2], p[3]);
    ins2s<4>(l, p[4], p[5]);
    ins2s<6>(l, p[6], p[7]);
    ins2s<8>(l, p[8], p[9]);
}

// phase1 neighborhood scan: bounds batched per z-slab (<=10 regs), gathers
// prefetched. Exec-masked per-lane template dispatch.
template<int S>
__device__ __forceinline__ void scan_slab(const float4* __restrict__ W,
                                          const int* __restrict__ st,
                                          int cx, int cy, int cz,
                                          float m2x, float m2y, float m2z,
                                          float q2, int qpos, int wv,
                                          int l[KNN])
{
    constexpr int Wd = 2 * S + 1;
    const int IMAX = 0x7FFFFFFF;
    const int xlo = max(cx - S, 0), xhi = min(cx + S, G - 1) + 1;
#pragma unroll
    for (int zi = 0; zi < Wd; ++zi) {
        const int az = cz + zi - S;
        int J0[Wd], J1[Wd];
#pragma unroll
        for (int yi = 0; yi < Wd; ++yi) {          // independent bound loads
            const int ay = cy + yi - S;
            const bool ok = ((unsigned)ay < G) && ((unsigned)az < G);
            const int cbase = (az << 10) | (ay << 5);
            J0[yi] = ok ? st[cbase + xlo] : 0;
            J1[yi] = ok ? st[cbase + xhi] : 0;
        }
#pragma unroll
        for (int yi = 0; yi < Wd; ++yi) {
            const int j1 = J1[yi];
            int j = J0[yi] + wv;
            if (j < j1) {
                float4 c4 = W[j];
                while (true) {
                    const int jn = j + WPB;
                    const bool more = jn < j1;
                    float4 nx;
                    if (more) nx = W[jn];          // prefetch
                    const float d2 = fmaf(m2x, c4.x,
                                     fmaf(m2y, c4.y,
                                     fmaf(m2z, c4.z, c4.w + q2)));
                    int key = (__float_as_int(d2) & MASK13) | j;
                    key = (j == qpos) ? IMAX : key;
                    ins1(l, key);
                    if (!more) break;
                    c4 = nx; j = jn;
                }
            }
        }
    }
}

// ---------------- the cooperative mega-kernel ----------------
__global__ __launch_bounds__(BLOCK)
void mega(const float* __restrict__ p1, const float* __restrict__ p2,
          float* __restrict__ out,
          float4* __restrict__ w, int* __restrict__ hist,
          int* __restrict__ starts, int* __restrict__ cellof,
          float4* __restrict__ wsorted, float4* __restrict__ p2s,
          int* __restrict__ nfail, int* __restrict__ worklist,
          int* __restrict__ blockTot)
{
    cg::grid_group grid = cg::this_grid();

    __shared__ int mv[WPB * KNN * QPB];      // 20 KB (stage E)
    __shared__ int wtot[8], wexcl[8], wred[8], sOff[1];

    const int b    = blockIdx.x;
    const int t    = threadIdx.x;
    const int gtid = b * BLOCK + t;          // 131072 threads
    const int lane = t & 63;
    const int wv   = t >> 6;
    const int IMAX = 0x7FFFFFFF;

    // ---- A: zero hist / out / nfail ----
    if (gtid < NB * NC) hist[gtid] = 0;
    if (gtid == 0) { out[0] = 0.0f; nfail[0] = 0; }
    grid.sync();

    // ---- B: pack + bin ----
    if (gtid < NB * NPTS) {
        const float x = p1[3 * gtid], y = p1[3 * gtid + 1], z = p1[3 * gtid + 2];
        w[gtid] = make_float4(x, y, z, fmaf(x, x, fmaf(y, y, z * z)));
        const int cx = min(max((int)floorf((x - BMIN) * INVH), 0), G - 1);
        const int cy = min(max((int)floorf((y - BMIN) * INVH), 0), G - 1);
        const int cz = min(max((int)floorf((z - BMIN) * INVH), 0), G - 1);
        const int c = (cz << 10) | (cy << 5) | cx;
        cellof[gtid] = c;
        atomicAdd(&hist[(gtid >> 13) * NC + c], 1);
    }
    grid.sync();

    // ---- C1: per-block exclusive scan of 256 cell counts ----
    const int batchC = b >> 7;               // 128 blocks per batch
    const int bb     = b & 127;
    int cnt = (t < 256) ? hist[b * 256 + t] : 0;
    int incl = cnt;
#pragma unroll
    for (int off = 1; off < 64; off <<= 1) {
        const int v = __shfl_up(incl, off);
        if (lane >= off) incl += v;
    }
    if (lane == 63) wtot[wv] = incl;
    __syncthreads();
    if (t < 8) {                              // tiny serial prefix of 8 totals
        int o = 0;
        for (int k = 0; k < t; ++k) o += wtot[k];
        wexcl[t] = o;
    }
    __syncthreads();
    const int excl = wexcl[wv] + incl - cnt;  // block-local exclusive prefix
    if (t == 0) blockTot[b] = wexcl[7] + wtot[7];
    if (t == 0 && bb == 0) starts[batchC * (NC + 1) + NC] = NPTS;  // sentinel
    grid.sync();

    // ---- C2: add inter-block offset, write starts ----
    {
        const int base = batchC << 7;
        int v = (t < bb) ? blockTot[base + t] : 0;
#pragma unroll
        for (int off = 32; off >= 1; off >>= 1) v += __shfl_xor(v, off);
        if (lane == 0) wred[wv] = v;
        __syncthreads();
        if (t == 0) {
            int o = 0;
#pragma unroll
            for (int k = 0; k < 8; ++k) o += wred[k];
            sOff[0] = o;
        }
        __syncthreads();
        if (t < 256)
            starts[batchC * (NC + 1) + bb * 256 + t] = excl + sOff[0];
    }
    grid.sync();

    // ---- D: scatter into cell-sorted order ----
    if (gtid < NB * NPTS) {
        const int bt = gtid >> 13;
        const int c = cellof[gtid];
        const int old = atomicSub(&hist[bt * NC + c], 1);
        const int pos = bt * NPTS + starts[bt * (NC + 1) + c] + old - 1;
        wsorted[pos] = w[gtid];
        p2s[pos] = make_float4(p2[3 * gtid], p2[3 * gtid + 1],
                               p2[3 * gtid + 2], 0.0f);
    }
    grid.sync();

    // ---- E: phase1 — per-lane adaptive neighborhood scan ----
    {
        const int batch = b >> 7;
        const int qpos  = ((b & 127) << 6) + lane;
        const float4* W  = wsorted + batch * NPTS;
        const float4* P2 = p2s + batch * NPTS;
        const int*    st = starts + batch * (NC + 1);

        const float4 qp = W[qpos];
        const int cx = min(max((int)floorf((qp.x - BMIN) * INVH), 0), G - 1);
        const int cy = min(max((int)floorf((qp.y - BMIN) * INVH), 0), G - 1);
        const int cz = min(max((int)floorf((qp.z - BMIN) * INVH), 0), G - 1);
        const float lox = BMIN + cx * H, loy = BMIN + cy * H, loz = BMIN + cz * H;
        const float df = fminf(fminf(fminf(qp.x - lox, lox + H - qp.x),
                                     fminf(qp.y - loy, loy + H - qp.y)),
                               fminf(qp.z - loz, loz + H - qp.z));
        const float m2x = -2.0f * qp.x, m2y = -2.0f * qp.y, m2z = -2.0f * qp.z;
        const float q2 = qp.w;
        const int sCov = (q2 > 4.8f) ? 2 : 1;  // per-lane reach (exec-masked)

        int l[KNN];
#pragma unroll
        for (int k = 0; k < KNN; ++k) l[k] = IMAX;

        if (sCov == 1)
            scan_slab<1>(W, st, cx, cy, cz, m2x, m2y, m2z, q2, qpos, wv, l);
        else
            scan_slab<2>(W, st, cx, cy, cz, m2x, m2y, m2z, q2, qpos, wv, l);

#pragma unroll
        for (int k = 0; k < KNN; ++k) mv[(wv * KNN + k) * QPB + lane] = l[k];
        __syncthreads();

        if (t < QPB) {
            int M[KNN];
#pragma unroll
            for (int k = 0; k < KNN; ++k) M[k] = IMAX;
#pragma unroll
            for (int e = 0; e < WPB; ++e) {
                int p[KNN];
#pragma unroll
                for (int k = 0; k < KNN; ++k) p[k] = mv[(e * KNN + k) * QPB + lane];
                merge_sorted(M, p);
            }
            const float tau = __int_as_float(M[KNN - 1] & MASK13);
            const float R = (float)sCov * H + df;
            const bool covered = (tau <= R * R * 0.996f);
            float v = 0.0f;
            if (covered) {
                float s1x = 0, s1y = 0, s1z = 0, s2x = 0, s2y = 0, s2z = 0;
#pragma unroll
                for (int k = 0; k < KNN; ++k) {
                    const int j = M[k] & (NPTS - 1);
                    const float4 c4 = W[j];
                    const float4 n2 = P2[j];
                    s1x += c4.x; s1y += c4.y; s1z += c4.z;
                    s2x += n2.x; s2y += n2.y; s2z += n2.z;
                }
                const float4 p2v = P2[qpos];
                const float dx = (s1x * 0.1f - qp.x) - (s2x * 0.1f - p2v.x);
                const float dy = (s1y * 0.1f - qp.y) - (s2y * 0.1f - p2v.y);
                const float dz = (s1z * 0.1f - qp.z) - (s2z * 0.1f - p2v.z);
                v = fabsf(dx) + fabsf(dy) + fabsf(dz);
            } else {
                const int wi = atomicAdd(nfail, 1);
                worklist[wi] = (batch << 16) | qpos;
            }
#pragma unroll
            for (int off = 32; off >= 1; off >>= 1) v += __shfl_down(v, off);
            if (t == 0)
                atomicAdd(out, v * (1.0f / (float)(NB * NPTS * 3)));
        }
    }
    grid.sync();

    // ---- F: phase2 — wave-per-failed-query exact brute force ----
    {
        const int nf = nfail[0];
        const int wid = b * WPB + wv;
        const int NW = GRID * WPB;               // 2048 waves
        float acc = 0.0f;
        for (int i = wid; i < nf; i += NW) {
            const int e = worklist[i];
            const int batch = e >> 16, qpos = e & 0xFFFF;
            const float4* W  = wsorted + batch * NPTS;
            const float4* P2 = p2s + batch * NPTS;
            const float4 qp = W[qpos];
            const float m2x = -2.0f * qp.x, m2y = -2.0f * qp.y, m2z = -2.0f * qp.z;
            const float q2 = qp.w;

            int l[KNN];
#pragma unroll
            for (int k = 0; k < KNN; ++k) l[k] = IMAX;
#pragma unroll 2
            for (int it = 0; it < NPTS / 128; ++it) {
                const int ja = it * 128 + lane, jb = ja + 64;
                const float4 ca = W[ja];
                const float4 cb = W[jb];
                const float da = fmaf(m2x, ca.x, fmaf(m2y, ca.y, fmaf(m2z, ca.z, ca.w + q2)));
                const float db = fmaf(m2x, cb.x, fmaf(m2y, cb.y, fmaf(m2z, cb.z, cb.w + q2)));
                int ka = (__float_as_int(da) & MASK13) | ja;
                int kb = (__float_as_int(db) & MASK13) | jb;
                ka = (ja == qpos) ? IMAX : ka;
                kb = (jb == qpos) ? IMAX : kb;
                ins2(l, ka, kb);
            }
            for (int off = 1; off < 64; off <<= 1) {
                int p[KNN];
#pragma unroll
                for (int k = 0; k < KNN; ++k) p[k] = __shfl_xor(l[k], off);
                merge_sorted(l, p);
            }
            float s1x = 0, s1y = 0, s1z = 0, s2x = 0, s2y = 0, s2z = 0;
#pragma unroll
            for (int k = 0; k < KNN; ++k) {
                const int j = l[k] & (NPTS - 1);
                const float4 c4 = W[j];
                const float4 n2 = P2[j];
                s1x += c4.x; s1y += c4.y; s1z += c4.z;
                s2x += n2.x; s2y += n2.y; s2z += n2.z;
            }
            const float4 p2v = P2[qpos];
            const float dx = (s1x * 0.1f - qp.x) - (s2x * 0.1f - p2v.x);
            const float dy = (s1y * 0.1f - qp.y) - (s2y * 0.1f - p2v.y);
            const float dz = (s1z * 0.1f - qp.z) - (s2z * 0.1f - p2v.z);
            if (lane == 0) acc += fabsf(dx) + fabsf(dy) + fabsf(dz);
        }
        if (lane == 0 && acc != 0.0f)
            atomicAdd(out, acc * (1.0f / (float)(NB * NPTS * 3)));
    }
}

// ---------------- round-2 fallback (O(N^2), verified) ----------------
constexpr int FB_WPB = 8;
constexpr int FB_BLOCK = QPB * FB_WPB;  // 512
constexpr int CHUNK = NPTS / FB_WPB;

__global__ void prep_pack(const float* __restrict__ p, float4* __restrict__ w) {
    const int i = blockIdx.x * blockDim.x + threadIdx.x;
    if (i < NB * NPTS) {
        const float x = p[3 * i], y = p[3 * i + 1], z = p[3 * i + 2];
        w[i] = make_float4(x, y, z, fmaf(x, x, fmaf(y, y, z * z)));
    }
}

__global__ __launch_bounds__(FB_BLOCK, 2)
void knn_lap(const float4* __restrict__ w1, const float* __restrict__ p2,
             float* __restrict__ out)
{
    __shared__ int mv[FB_WPB * KNN * QPB];
    const int batch = blockIdx.x >> 7;
    const int qbase = (blockIdx.x & 127) << 6;
    const int lane  = threadIdx.x & 63;
    const int wv    = __builtin_amdgcn_readfirstlane(threadIdx.x >> 6);
    const int query = qbase + lane;
    const float4* Wb = w1 + batch * NPTS;
    const float4 qp = Wb[query];
    const float m2x = -2.0f * qp.x, m2y = -2.0f * qp.y, m2z = -2.0f * qp.z;
    const float q2 = qp.w;
    const int IMAX = 0x7FFFFFFF;
    int l[KNN];
#pragma unroll
    for (int k = 0; k < KNN; ++k) l[k] = IMAX;
    const int c0 = wv * CHUNK;
    const float4* cand = Wb + c0;
#pragma unroll 4
    for (int i = 0; i < CHUNK; i += 2) {
        const float4 ca = cand[i];
        const float4 cb = cand[i + 1];
        const int ja = c0 + i, jb = ja + 1;
        const float da = fmaf(m2x, ca.x, fmaf(m2y, ca.y, fmaf(m2z, ca.z, ca.w + q2)));
        const float db = fmaf(m2x, cb.x, fmaf(m2y, cb.y, fmaf(m2z, cb.z, cb.w + q2)));
        int ka = (__float_as_int(da) & MASK13) | ja;
        int kb = (__float_as_int(db) & MASK13) | jb;
        ka = (ja == query) ? IMAX : ka;
        kb = (jb == query) ? IMAX : kb;
        ins2(l, ka, kb);
    }
#pragma unroll
    for (int k = 0; k < KNN; ++k) mv[(wv * KNN + k) * QPB + lane] = l[k];
    __syncthreads();
    if (threadIdx.x < QPB) {
        int m[KNN];
#pragma unroll
        for (int k = 0; k < KNN; ++k) m[k] = IMAX;
#pragma unroll
        for (int e = 0; e < FB_WPB; ++e) {
            int p[KNN];
#pragma unroll
            for (int k = 0; k < KNN; ++k) p[k] = mv[(e * KNN + k) * QPB + lane];
            merge_sorted(m, p);
        }
        const float* P2b = p2 + (size_t)batch * NPTS * 3;
        float s1x = 0, s1y = 0, s1z = 0, s2x = 0, s2y = 0, s2z = 0;
#pragma unroll
        for (int k = 0; k < KNN; ++k) {
            const int j = m[k] & (NPTS - 1);
            const float4 c = Wb[j];
            s1x += c.x; s1y += c.y; s1z += c.z;
            s2x += P2b[3 * j + 0]; s2y += P2b[3 * j + 1]; s2z += P2b[3 * j + 2];
        }
        const int q = qbase + threadIdx.x;
        const float p2x = P2b[3 * q + 0], p2y = P2b[3 * q + 1], p2z = P2b[3 * q + 2];
        const float dx = (s1x * 0.1f - qp.x) - (s2x * 0.1f - p2x);
        const float dy = (s1y * 0.1f - qp.y) - (s2y * 0.1f - p2y);
        const float dz = (s1z * 0.1f - qp.z) - (s2z * 0.1f - p2z);
        float v = fabsf(dx) + fabsf(dy) + fabsf(dz);
#pragma unroll
        for (int off = 32; off >= 1; off >>= 1) v += __shfl_down(v, off);
        if (threadIdx.x == 0)
            atomicAdd(out, v * (1.0f / (float)(NB * NPTS * 3)));
    }
}

// ---------------- launcher ----------------
extern "C" void kernel_launch(void* const* d_in, const int* in_sizes, int n_in,
                              void* d_out, int out_size, void* d_ws, size_t ws_size,
                              hipStream_t stream) {
    const float* p1 = (const float*)d_in[0];
    const float* p2 = (const float*)d_in[1];
    float* out = (float*)d_out;

    size_t off = 0;
    float4* w       = (float4*)d_ws;                off += (size_t)NB * NPTS * 16;
    int*    hist    = (int*)((char*)d_ws + off);    off += (size_t)NB * NC * 4;
    int*    starts  = (int*)((char*)d_ws + off);    off += (size_t)NB * (NC + 1) * 4 + 8;
    int*    cellof  = (int*)((char*)d_ws + off);    off += (size_t)NB * NPTS * 4;
    float4* wsorted = (float4*)((char*)d_ws + off); off += (size_t)NB * NPTS * 16;
    float4* p2s     = (float4*)((char*)d_ws + off); off += (size_t)NB * NPTS * 16;
    int*    nfail   = (int*)((char*)d_ws + off);    off += 16;
    int*    worklist= (int*)((char*)d_ws + off);    off += (size_t)NB * NPTS * 4;
    int*    blockTot= (int*)((char*)d_ws + off);    off += (size_t)GRID * 4;

    if (ws_size < off) {  // fallback: round-2 brute force
        hipMemsetAsync(out, 0, sizeof(float), stream);
        prep_pack<<<(NB * NPTS + 255) / 256, 256, 0, stream>>>(p1, w);
        knn_lap<<<NB * (NPTS / QPB), FB_BLOCK, 0, stream>>>(w, p2, out);
        return;
    }

    void* args[] = { (void*)&p1, (void*)&p2, (void*)&out, (void*)&w,
                     (void*)&hist, (void*)&starts, (void*)&cellof,
                     (void*)&wsorted, (void*)&p2s, (void*)&nfail,
                     (void*)&worklist, (void*)&blockTot };
    hipLaunchCooperativeKernel((void*)mega, dim3(GRID), dim3(BLOCK),
                               args, 0, stream);
}

// Round 12
// 147.657 us; speedup vs baseline: 1.8007x; 1.8007x over previous
//
#include <hip/hip_runtime.h>
#include <math.h>

// PointLaplacianLoss — grid-pruned exact KNN, round 12.
//
// Round-11 lesson: grid.sync() costs ~25 us each on 8-XCD MI355X — the
// cooperative mega-kernel was 204 us. Dispatch boundaries are CHEAPER than
// grid syncs here. This round consolidates without grid sync:
//   * phase2 folded into phase1 as BLOCK-LOCAL cleanup (failed lanes of this
//     block's 64 queries -> LDS list -> block's own 8 waves brute-force them).
//     Kills the phase2 dispatch + worklist + nfail.
//   * p2s scattered array dropped: scatter writes wsorted + 4B sIdx (orig
//     index); epilogue gathers p2 via sIdx (10 gathers/query, ILP-covered).
//   * pipeline = 5 dispatches: memset(hist), pack_bin, scan_cells, scatter,
//     phase1(+cleanup).

constexpr int NPTS  = 8192;
constexpr int NB    = 2;
constexpr int KNN   = 10;
constexpr int QPB   = 64;
constexpr int WPB   = 8;
constexpr int BLOCK = QPB * WPB;        // 512
constexpr int MASK13 = 0xFFFFE000;

constexpr int   G    = 32;
constexpr int   NC   = G * G * G;
constexpr float BMIN = -5.5f;
constexpr float BW   = 11.0f;
constexpr float H    = BW / G;          // 0.34375
constexpr float INVH = (float)G / BW;

// ---------------- selection helpers ----------------
__device__ __forceinline__ void ins1(int l[KNN], int x) {
#pragma unroll
    for (int k = KNN - 1; k > 0; --k) l[k] = min(l[k], max(l[k - 1], x));
    l[0] = min(l[0], x);
}
__device__ __forceinline__ void ins2(int l[KNN], int a, int b) {
    const int b0 = min(a, b), b1 = max(a, b);
#pragma unroll
    for (int k = KNN - 1; k >= 2; --k)
        l[k] = min(l[k], min(max(l[k - 1], b0), max(l[k - 2], b1)));
    l[1] = min(l[1], min(max(l[0], b0), b1));
    l[0] = min(l[0], b0);
}
template<int S>
__device__ __forceinline__ void ins2s(int l[KNN], int a, int b) {
    const int b0 = min(a, b), b1 = max(a, b);
#pragma unroll
    for (int k = KNN - 1; k >= S + 2; --k)
        l[k] = min(l[k], min(max(l[k - 1], b0), max(l[k - 2], b1)));
    l[S + 1] = min(l[S + 1], min(max(l[S], b0), b1));
    l[S] = min(l[S], b0);
}
__device__ __forceinline__ void merge_sorted(int l[KNN], const int p[KNN]) {
    ins2s<0>(l, p[0], p[1]);
    ins2s<2>(l, p[2], p[3]);
    ins2s<4>(l, p[4], p[5]);
    ins2s<6>(l, p[6], p[7]);
    ins2s<8>(l, p[8], p[9]);
}

// ---------------- build kernels ----------------
__global__ void pack_bin(const float* __restrict__ p1, float4* __restrict__ w,
                         int* __restrict__ hist, int* __restrict__ cellof,
                         float* __restrict__ out) {
    const int i = blockIdx.x * blockDim.x + threadIdx.x;
    if (i >= NB * NPTS) return;
    if (i == 0) out[0] = 0.0f;
    const float x = p1[3 * i], y = p1[3 * i + 1], z = p1[3 * i + 2];
    w[i] = make_float4(x, y, z, fmaf(x, x, fmaf(y, y, z * z)));
    const int cx = min(max((int)floorf((x - BMIN) * INVH), 0), G - 1);
    const int cy = min(max((int)floorf((y - BMIN) * INVH), 0), G - 1);
    const int cz = min(max((int)floorf((z - BMIN) * INVH), 0), G - 1);
    const int c = (cz << 10) | (cy << 5) | cx;
    cellof[i] = c;
    atomicAdd(&hist[(i >> 13) * NC + c], 1);
}

__global__ __launch_bounds__(1024)
void scan_cells(const int* __restrict__ hist, int* __restrict__ starts) {
    __shared__ int wsum[16];
    const int b = blockIdx.x, t = threadIdx.x;
    const int* hb = hist + b * NC;
    int* sb = starts + b * (NC + 1);
    const int c0 = t * 32;
    int loc[32]; int sum = 0;
#pragma unroll
    for (int j = 0; j < 32; ++j) { loc[j] = hb[c0 + j]; sum += loc[j]; }
    const int lane = t & 63, wvi = t >> 6;
    int incl = sum;
#pragma unroll
    for (int off = 1; off < 64; off <<= 1) {
        const int v = __shfl_up(incl, off);
        if (lane >= off) incl += v;
    }
    if (lane == 63) wsum[wvi] = incl;
    __syncthreads();
    if (t < 16) {
        const int v = wsum[t];
        int iv = v;
#pragma unroll
        for (int off = 1; off < 16; off <<= 1) {
            const int u = __shfl_up(iv, off);
            if (t >= off) iv += u;
        }
        wsum[t] = iv - v;
    }
    __syncthreads();
    int run = wsum[wvi] + incl - sum;
#pragma unroll
    for (int j = 0; j < 32; ++j) { sb[c0 + j] = run; run += loc[j]; }
    if (t == 1023) sb[NC] = run;
}

__global__ void scatter_all(const int* __restrict__ cellof,
                            const int* __restrict__ starts,
                            int* __restrict__ hist,
                            const float4* __restrict__ w,
                            float4* __restrict__ wsorted,
                            int* __restrict__ sIdx) {
    const int i = blockIdx.x * blockDim.x + threadIdx.x;
    if (i >= NB * NPTS) return;
    const int b = i >> 13;
    const int c = cellof[i];
    const int old = atomicSub(&hist[b * NC + c], 1);
    const int pos = b * NPTS + starts[b * (NC + 1) + c] + old - 1;
    wsorted[pos] = w[i];
    sIdx[pos] = i & (NPTS - 1);
}

// batched-bounds neighborhood scan (round 10): all run bounds loaded as
// independent loads before the first gather; gathers prefetched.
template<int S>
__device__ __forceinline__ void scan_batched(const float4* __restrict__ W,
                                             const int* __restrict__ st,
                                             int cx, int cy, int cz,
                                             float m2x, float m2y, float m2z,
                                             float q2, int qpos, int wv,
                                             int l[KNN])
{
    constexpr int Wd = 2 * S + 1;
    constexpr int R  = Wd * Wd;
    const int IMAX = 0x7FFFFFFF;
    int J0[R], J1[R];
#pragma unroll
    for (int r = 0; r < R; ++r) {
        const int dy = r % Wd - S, dz = r / Wd - S;   // compile-time
        const int ay = cy + dy, az = cz + dz;
        const bool ok = ((unsigned)ay < G) && ((unsigned)az < G);
        const int cbase = (az << 10) | (ay << 5);
        const int lo = cbase + max(cx - S, 0);
        const int hi = cbase + min(cx + S, G - 1) + 1;
        J0[r] = ok ? st[lo] : 0;
        J1[r] = ok ? st[hi] : 0;
    }
#pragma unroll
    for (int r = 0; r < R; ++r) {
        const int j1 = J1[r];
        int j = J0[r] + wv;
        if (j < j1) {
            float4 c4 = W[j];
            while (true) {
                const int jn = j + WPB;
                const bool more = jn < j1;
                float4 nx;
                if (more) nx = W[jn];
                const float d2 = fmaf(m2x, c4.x,
                                 fmaf(m2y, c4.y,
                                 fmaf(m2z, c4.z, c4.w + q2)));
                int key = (__float_as_int(d2) & MASK13) | j;
                key = (j == qpos) ? IMAX : key;
                ins1(l, key);
                if (!more) break;
                c4 = nx; j = jn;
            }
        }
    }
}

// ---------------- phase 1 + block-local cleanup ----------------
__global__ __launch_bounds__(BLOCK)
void phase1(const float4* __restrict__ wsorted, const int* __restrict__ sIdx,
            const float* __restrict__ p2, const int* __restrict__ starts,
            float* __restrict__ out)
{
    __shared__ int mv[WPB * KNN * QPB];      // 20 KB
    __shared__ int failList[QPB];
    __shared__ int nFail;
    __shared__ float bsum;

    const int batch = blockIdx.x >> 7;
    const int t     = threadIdx.x;
    const int lane  = t & 63;
    const int wv    = __builtin_amdgcn_readfirstlane(t >> 6);
    const int qpos  = ((blockIdx.x & 127) << 6) + lane;

    const float4* W  = wsorted + batch * NPTS;
    const int*    sI = sIdx + batch * NPTS;
    const float*  P2 = p2 + (size_t)batch * NPTS * 3;
    const int*    st = starts + batch * (NC + 1);

    if (t == 0) { nFail = 0; bsum = 0.0f; }

    const float4 qp = W[qpos];
    const int cx = min(max((int)floorf((qp.x - BMIN) * INVH), 0), G - 1);
    const int cy = min(max((int)floorf((qp.y - BMIN) * INVH), 0), G - 1);
    const int cz = min(max((int)floorf((qp.z - BMIN) * INVH), 0), G - 1);
    const float lox = BMIN + cx * H, loy = BMIN + cy * H, loz = BMIN + cz * H;
    const float df = fminf(fminf(fminf(qp.x - lox, lox + H - qp.x),
                                 fminf(qp.y - loy, loy + H - qp.y)),
                           fminf(qp.z - loz, loz + H - qp.z));
    const float m2x = -2.0f * qp.x, m2y = -2.0f * qp.y, m2z = -2.0f * qp.z;
    const float q2 = qp.w;
    const int IMAX = 0x7FFFFFFF;

    const int sCov = (q2 > 4.8f) ? 2 : 1;    // per-lane reach (exec-masked)

    int l[KNN];
#pragma unroll
    for (int k = 0; k < KNN; ++k) l[k] = IMAX;

    if (sCov == 1)
        scan_batched<1>(W, st, cx, cy, cz, m2x, m2y, m2z, q2, qpos, wv, l);
    else
        scan_batched<2>(W, st, cx, cy, cz, m2x, m2y, m2z, q2, qpos, wv, l);

#pragma unroll
    for (int k = 0; k < KNN; ++k) mv[(wv * KNN + k) * QPB + lane] = l[k];
    __syncthreads();

    if (t < QPB) {                           // wave 0: lane == query
        int M[KNN];
#pragma unroll
        for (int k = 0; k < KNN; ++k) M[k] = IMAX;
#pragma unroll
        for (int e = 0; e < WPB; ++e) {
            int p[KNN];
#pragma unroll
            for (int k = 0; k < KNN; ++k) p[k] = mv[(e * KNN + k) * QPB + lane];
            merge_sorted(M, p);
        }

        const float tau = __int_as_float(M[KNN - 1] & MASK13);
        const float R = (float)sCov * H + df;
        const bool covered = (tau <= R * R * 0.996f);
        float v = 0.0f;
        if (covered) {
            float s1x = 0, s1y = 0, s1z = 0, s2x = 0, s2y = 0, s2z = 0;
#pragma unroll
            for (int k = 0; k < KNN; ++k) {
                const int j = M[k] & (NPTS - 1);
                const float4 c4 = W[j];
                const int oi = sI[j];
                s1x += c4.x; s1y += c4.y; s1z += c4.z;
                s2x += P2[3 * oi + 0];
                s2y += P2[3 * oi + 1];
                s2z += P2[3 * oi + 2];
            }
            const int oq = sI[qpos];
            const float p2x = P2[3 * oq + 0];
            const float p2y = P2[3 * oq + 1];
            const float p2z = P2[3 * oq + 2];
            const float dx = (s1x * 0.1f - qp.x) - (s2x * 0.1f - p2x);
            const float dy = (s1y * 0.1f - qp.y) - (s2y * 0.1f - p2y);
            const float dz = (s1z * 0.1f - qp.z) - (s2z * 0.1f - p2z);
            v = fabsf(dx) + fabsf(dy) + fabsf(dz);
        }
        // collect failed lanes into LDS (wave-0-wide ballot, rank by prefix)
        const unsigned long long fm = __ballot(!covered);
        if (!covered) {
            const int rank = __popcll(fm & ((1ull << lane) - 1ull));
            failList[rank] = lane;
        }
        if (lane == 0) nFail = __popcll(fm);
        // covered-query partial sum
#pragma unroll
        for (int off = 32; off >= 1; off >>= 1) v += __shfl_down(v, off);
        if (lane == 0) bsum = v;
    }
    __syncthreads();

    // ---- block-local cleanup: this block's waves brute-force its failures ----
    const int nf = nFail;
    float acc = 0.0f;
    for (int i = wv; i < nf; i += WPB) {
        const int fq = ((blockIdx.x & 127) << 6) + failList[i];
        const float4 fqp = W[fq];
        const float f2x = -2.0f * fqp.x, f2y = -2.0f * fqp.y, f2z = -2.0f * fqp.z;
        const float fq2 = fqp.w;

        int fl[KNN];
#pragma unroll
        for (int k = 0; k < KNN; ++k) fl[k] = IMAX;
#pragma unroll 2
        for (int it = 0; it < NPTS / 128; ++it) {
            const int ja = it * 128 + lane, jb = ja + 64;
            const float4 ca = W[ja];
            const float4 cb = W[jb];
            const float da = fmaf(f2x, ca.x, fmaf(f2y, ca.y, fmaf(f2z, ca.z, ca.w + fq2)));
            const float db = fmaf(f2x, cb.x, fmaf(f2y, cb.y, fmaf(f2z, cb.z, cb.w + fq2)));
            int ka = (__float_as_int(da) & MASK13) | ja;
            int kb = (__float_as_int(db) & MASK13) | jb;
            ka = (ja == fq) ? IMAX : ka;
            kb = (jb == fq) ? IMAX : kb;
            ins2(fl, ka, kb);
        }
        for (int off = 1; off < 64; off <<= 1) {
            int p[KNN];
#pragma unroll
            for (int k = 0; k < KNN; ++k) p[k] = __shfl_xor(fl[k], off);
            merge_sorted(fl, p);
        }
        float s1x = 0, s1y = 0, s1z = 0, s2x = 0, s2y = 0, s2z = 0;
#pragma unroll
        for (int k = 0; k < KNN; ++k) {
            const int j = fl[k] & (NPTS - 1);
            const float4 c4 = W[j];
            const int oi = sI[j];
            s1x += c4.x; s1y += c4.y; s1z += c4.z;
            s2x += P2[3 * oi + 0];
            s2y += P2[3 * oi + 1];
            s2z += P2[3 * oi + 2];
        }
        const int oq = sI[fq];
        const float dx = (s1x * 0.1f - fqp.x) - (s2x * 0.1f - P2[3 * oq + 0]);
        const float dy = (s1y * 0.1f - fqp.y) - (s2y * 0.1f - P2[3 * oq + 1]);
        const float dz = (s1z * 0.1f - fqp.z) - (s2z * 0.1f - P2[3 * oq + 2]);
        if (lane == 0) acc += fabsf(dx) + fabsf(dy) + fabsf(dz);
    }
    if (lane == 0 && acc != 0.0f) atomicAdd(&bsum, acc);
    __syncthreads();
    if (t == 0)
        atomicAdd(out, bsum * (1.0f / (float)(NB * NPTS * 3)));
}

// ---------------- round-2 fallback (O(N^2), verified) ----------------
constexpr int CHUNK = NPTS / WPB;

__global__ void prep_pack(const float* __restrict__ p, float4* __restrict__ w) {
    const int i = blockIdx.x * blockDim.x + threadIdx.x;
    if (i < NB * NPTS) {
        const float x = p[3 * i], y = p[3 * i + 1], z = p[3 * i + 2];
        w[i] = make_float4(x, y, z, fmaf(x, x, fmaf(y, y, z * z)));
    }
}

__global__ __launch_bounds__(BLOCK, 2)
void knn_lap(const float4* __restrict__ w1, const float* __restrict__ p2,
             float* __restrict__ out)
{
    __shared__ int mv[WPB * KNN * QPB];
    const int batch = blockIdx.x >> 7;
    const int qbase = (blockIdx.x & 127) << 6;
    const int lane  = threadIdx.x & 63;
    const int wv    = __builtin_amdgcn_readfirstlane(threadIdx.x >> 6);
    const int query = qbase + lane;
    const float4* Wb = w1 + batch * NPTS;
    const float4 qp = Wb[query];
    const float m2x = -2.0f * qp.x, m2y = -2.0f * qp.y, m2z = -2.0f * qp.z;
    const float q2 = qp.w;
    const int IMAX = 0x7FFFFFFF;
    int l[KNN];
#pragma unroll
    for (int k = 0; k < KNN; ++k) l[k] = IMAX;
    const int c0 = wv * CHUNK;
    const float4* cand = Wb + c0;
#pragma unroll 4
    for (int i = 0; i < CHUNK; i += 2) {
        const float4 ca = cand[i];
        const float4 cb = cand[i + 1];
        const int ja = c0 + i, jb = ja + 1;
        const float da = fmaf(m2x, ca.x, fmaf(m2y, ca.y, fmaf(m2z, ca.z, ca.w + q2)));
        const float db = fmaf(m2x, cb.x, fmaf(m2y, cb.y, fmaf(m2z, cb.z, cb.w + q2)));
        int ka = (__float_as_int(da) & MASK13) | ja;
        int kb = (__float_as_int(db) & MASK13) | jb;
        ka = (ja == query) ? IMAX : ka;
        kb = (jb == query) ? IMAX : kb;
        ins2(l, ka, kb);
    }
#pragma unroll
    for (int k = 0; k < KNN; ++k) mv[(wv * KNN + k) * QPB + lane] = l[k];
    __syncthreads();
    if (threadIdx.x < QPB) {
        int m[KNN];
#pragma unroll
        for (int k = 0; k < KNN; ++k) m[k] = IMAX;
#pragma unroll
        for (int e = 0; e < WPB; ++e) {
            int p[KNN];
#pragma unroll
            for (int k = 0; k < KNN; ++k) p[k] = mv[(e * KNN + k) * QPB + lane];
            merge_sorted(m, p);
        }
        const float* P2b = p2 + (size_t)batch * NPTS * 3;
        float s1x = 0, s1y = 0, s1z = 0, s2x = 0, s2y = 0, s2z = 0;
#pragma unroll
        for (int k = 0; k < KNN; ++k) {
            const int j = m[k] & (NPTS - 1);
            const float4 c = Wb[j];
            s1x += c.x; s1y += c.y; s1z += c.z;
            s2x += P2b[3 * j + 0]; s2y += P2b[3 * j + 1]; s2z += P2b[3 * j + 2];
        }
        const int q = qbase + threadIdx.x;
        const float p2x = P2b[3 * q + 0], p2y = P2b[3 * q + 1], p2z = P2b[3 * q + 2];
        const float dx = (s1x * 0.1f - qp.x) - (s2x * 0.1f - p2x);
        const float dy = (s1y * 0.1f - qp.y) - (s2y * 0.1f - p2y);
        const float dz = (s1z * 0.1f - qp.z) - (s2z * 0.1f - p2z);
        float v = fabsf(dx) + fabsf(dy) + fabsf(dz);
#pragma unroll
        for (int off = 32; off >= 1; off >>= 1) v += __shfl_down(v, off);
        if (threadIdx.x == 0)
            atomicAdd(out, v * (1.0f / (float)(NB * NPTS * 3)));
    }
}

// ---------------- launcher ----------------
extern "C" void kernel_launch(void* const* d_in, const int* in_sizes, int n_in,
                              void* d_out, int out_size, void* d_ws, size_t ws_size,
                              hipStream_t stream) {
    const float* p1 = (const float*)d_in[0];
    const float* p2 = (const float*)d_in[1];
    float* out = (float*)d_out;

    size_t off = 0;
    float4* w       = (float4*)d_ws;                off += (size_t)NB * NPTS * 16;
    int*    hist    = (int*)((char*)d_ws + off);    off += (size_t)NB * NC * 4;
    int*    starts  = (int*)((char*)d_ws + off);    off += (size_t)NB * (NC + 1) * 4 + 8;
    int*    cellof  = (int*)((char*)d_ws + off);    off += (size_t)NB * NPTS * 4;
    float4* wsorted = (float4*)((char*)d_ws + off); off += (size_t)NB * NPTS * 16;
    int*    sIdx    = (int*)((char*)d_ws + off);    off += (size_t)NB * NPTS * 4;

    if (ws_size < off) {  // fallback: round-2 brute force
        hipMemsetAsync(out, 0, sizeof(float), stream);
        prep_pack<<<(NB * NPTS + 255) / 256, 256, 0, stream>>>(p1, w);
        knn_lap<<<NB * (NPTS / QPB), BLOCK, 0, stream>>>(w, p2, out);
        return;
    }

    hipMemsetAsync(hist, 0, (size_t)NB * NC * 4, stream);
    pack_bin<<<(NB * NPTS + 255) / 256, 256, 0, stream>>>(p1, w, hist, cellof, out);
    scan_cells<<<NB, 1024, 0, stream>>>(hist, starts);
    scatter_all<<<(NB * NPTS + 255) / 256, 256, 0, stream>>>(cellof, starts, hist,
                                                             w, wsorted, sIdx);
    phase1<<<NB * (NPTS / QPB), BLOCK, 0, stream>>>(wsorted, sIdx, p2, starts, out);
}

// Round 13
// 120.860 us; speedup vs baseline: 2.1999x; 1.2217x over previous
//
#include <hip/hip_runtime.h>
#include <math.h>

// PointLaplacianLoss — grid-pruned exact KNN, round 13.
//
// Round-12 lesson: block-local cleanup concentrates the ~500 shell failures
// into a few tail blocks (one block = 8 brute queries/wave serial tail,
// +35 us). Restore grid-wide phase2 (2048 waves, ~1 failure each). Keep
// round-10's best-measured phase1 (WPB=16, batched bounds) and round-12's
// sIdx optimization (scatter writes wsorted + 4B index instead of a second
// scattered float4 stream). Pipeline: memset, pack_bin, scan_cells,
// scatter_all, phase1, phase2.

constexpr int NPTS  = 8192;
constexpr int NB    = 2;
constexpr int KNN   = 10;
constexpr int QPB   = 64;
constexpr int WPB   = 16;               // wave-slices per query
constexpr int BLOCK = QPB * WPB;        // 1024
constexpr int MASK13 = 0xFFFFE000;

constexpr int   G    = 32;
constexpr int   NC   = G * G * G;
constexpr float BMIN = -5.5f;
constexpr float BW   = 11.0f;
constexpr float H    = BW / G;          // 0.34375
constexpr float INVH = (float)G / BW;

// ---------------- selection helpers ----------------
__device__ __forceinline__ void ins1(int l[KNN], int x) {
#pragma unroll
    for (int k = KNN - 1; k > 0; --k) l[k] = min(l[k], max(l[k - 1], x));
    l[0] = min(l[0], x);
}
__device__ __forceinline__ void ins2(int l[KNN], int a, int b) {
    const int b0 = min(a, b), b1 = max(a, b);
#pragma unroll
    for (int k = KNN - 1; k >= 2; --k)
        l[k] = min(l[k], min(max(l[k - 1], b0), max(l[k - 2], b1)));
    l[1] = min(l[1], min(max(l[0], b0), b1));
    l[0] = min(l[0], b0);
}
template<int S>
__device__ __forceinline__ void ins2s(int l[KNN], int a, int b) {
    const int b0 = min(a, b), b1 = max(a, b);
#pragma unroll
    for (int k = KNN - 1; k >= S + 2; --k)
        l[k] = min(l[k], min(max(l[k - 1], b0), max(l[k - 2], b1)));
    l[S + 1] = min(l[S + 1], min(max(l[S], b0), b1));
    l[S] = min(l[S], b0);
}
__device__ __forceinline__ void merge_sorted(int l[KNN], const int p[KNN]) {
    ins2s<0>(l, p[0], p[1]);
    ins2s<2>(l, p[2], p[3]);
    ins2s<4>(l, p[4], p[5]);
    ins2s<6>(l, p[6], p[7]);
    ins2s<8>(l, p[8], p[9]);
}

// ---------------- build kernels ----------------
__global__ void pack_bin(const float* __restrict__ p1, float4* __restrict__ w,
                         int* __restrict__ hist, int* __restrict__ cellof,
                         float* __restrict__ out, int* __restrict__ nfail) {
    const int i = blockIdx.x * blockDim.x + threadIdx.x;
    if (i >= NB * NPTS) return;
    if (i == 0) { out[0] = 0.0f; nfail[0] = 0; }
    const float x = p1[3 * i], y = p1[3 * i + 1], z = p1[3 * i + 2];
    w[i] = make_float4(x, y, z, fmaf(x, x, fmaf(y, y, z * z)));
    const int cx = min(max((int)floorf((x - BMIN) * INVH), 0), G - 1);
    const int cy = min(max((int)floorf((y - BMIN) * INVH), 0), G - 1);
    const int cz = min(max((int)floorf((z - BMIN) * INVH), 0), G - 1);
    const int c = (cz << 10) | (cy << 5) | cx;
    cellof[i] = c;
    atomicAdd(&hist[(i >> 13) * NC + c], 1);
}

__global__ __launch_bounds__(1024)
void scan_cells(const int* __restrict__ hist, int* __restrict__ starts) {
    __shared__ int wsum[16];
    const int b = blockIdx.x, t = threadIdx.x;
    const int* hb = hist + b * NC;
    int* sb = starts + b * (NC + 1);
    const int c0 = t * 32;
    int loc[32]; int sum = 0;
#pragma unroll
    for (int j = 0; j < 32; ++j) { loc[j] = hb[c0 + j]; sum += loc[j]; }
    const int lane = t & 63, wvi = t >> 6;
    int incl = sum;
#pragma unroll
    for (int off = 1; off < 64; off <<= 1) {
        const int v = __shfl_up(incl, off);
        if (lane >= off) incl += v;
    }
    if (lane == 63) wsum[wvi] = incl;
    __syncthreads();
    if (t < 16) {
        const int v = wsum[t];
        int iv = v;
#pragma unroll
        for (int off = 1; off < 16; off <<= 1) {
            const int u = __shfl_up(iv, off);
            if (t >= off) iv += u;
        }
        wsum[t] = iv - v;
    }
    __syncthreads();
    int run = wsum[wvi] + incl - sum;
#pragma unroll
    for (int j = 0; j < 32; ++j) { sb[c0 + j] = run; run += loc[j]; }
    if (t == 1023) sb[NC] = run;
}

__global__ void scatter_all(const int* __restrict__ cellof,
                            const int* __restrict__ starts,
                            int* __restrict__ hist,
                            const float4* __restrict__ w,
                            float4* __restrict__ wsorted,
                            int* __restrict__ sIdx) {
    const int i = blockIdx.x * blockDim.x + threadIdx.x;
    if (i >= NB * NPTS) return;
    const int b = i >> 13;
    const int c = cellof[i];
    const int old = atomicSub(&hist[b * NC + c], 1);
    const int pos = b * NPTS + starts[b * (NC + 1) + c] + old - 1;
    wsorted[pos] = w[i];
    sIdx[pos] = i & (NPTS - 1);
}

// batched-bounds neighborhood scan (round 10): all run bounds loaded as
// independent loads before the first gather; gathers prefetched.
template<int S>
__device__ __forceinline__ void scan_batched(const float4* __restrict__ W,
                                             const int* __restrict__ st,
                                             int cx, int cy, int cz,
                                             float m2x, float m2y, float m2z,
                                             float q2, int qpos, int wv,
                                             int l[KNN])
{
    constexpr int Wd = 2 * S + 1;
    constexpr int R  = Wd * Wd;
    const int IMAX = 0x7FFFFFFF;
    int J0[R], J1[R];
#pragma unroll
    for (int r = 0; r < R; ++r) {
        const int dy = r % Wd - S, dz = r / Wd - S;   // compile-time
        const int ay = cy + dy, az = cz + dz;
        const bool ok = ((unsigned)ay < G) && ((unsigned)az < G);
        const int cbase = (az << 10) | (ay << 5);
        const int lo = cbase + max(cx - S, 0);
        const int hi = cbase + min(cx + S, G - 1) + 1;
        J0[r] = ok ? st[lo] : 0;
        J1[r] = ok ? st[hi] : 0;
    }
#pragma unroll
    for (int r = 0; r < R; ++r) {
        const int j1 = J1[r];
        int j = J0[r] + wv;
        if (j < j1) {
            float4 c4 = W[j];
            while (true) {
                const int jn = j + WPB;
                const bool more = jn < j1;
                float4 nx;
                if (more) nx = W[jn];
                const float d2 = fmaf(m2x, c4.x,
                                 fmaf(m2y, c4.y,
                                 fmaf(m2z, c4.z, c4.w + q2)));
                int key = (__float_as_int(d2) & MASK13) | j;
                key = (j == qpos) ? IMAX : key;
                ins1(l, key);
                if (!more) break;
                c4 = nx; j = jn;
            }
        }
    }
}

// ---------------- phase 1 ----------------
__global__ __launch_bounds__(BLOCK)
void phase1(const float4* __restrict__ wsorted, const int* __restrict__ sIdx,
            const float* __restrict__ p2, const int* __restrict__ starts,
            float* __restrict__ out,
            int* __restrict__ nfail, int* __restrict__ worklist)
{
    __shared__ int mv[WPB * KNN * QPB];      // 40 KB

    const int batch = blockIdx.x >> 7;
    const int lane  = threadIdx.x & 63;
    const int wv    = __builtin_amdgcn_readfirstlane(threadIdx.x >> 6);
    const int qpos  = ((blockIdx.x & 127) << 6) + lane;

    const float4* W  = wsorted + batch * NPTS;
    const int*    sI = sIdx + batch * NPTS;
    const float*  P2 = p2 + (size_t)batch * NPTS * 3;
    const int*    st = starts + batch * (NC + 1);

    const float4 qp = W[qpos];
    const int cx = min(max((int)floorf((qp.x - BMIN) * INVH), 0), G - 1);
    const int cy = min(max((int)floorf((qp.y - BMIN) * INVH), 0), G - 1);
    const int cz = min(max((int)floorf((qp.z - BMIN) * INVH), 0), G - 1);
    const float lox = BMIN + cx * H, loy = BMIN + cy * H, loz = BMIN + cz * H;
    const float df = fminf(fminf(fminf(qp.x - lox, lox + H - qp.x),
                                 fminf(qp.y - loy, loy + H - qp.y)),
                           fminf(qp.z - loz, loz + H - qp.z));
    const float m2x = -2.0f * qp.x, m2y = -2.0f * qp.y, m2z = -2.0f * qp.z;
    const float q2 = qp.w;
    const int IMAX = 0x7FFFFFFF;

    const int sCov = (q2 > 4.8f) ? 2 : 1;    // per-lane reach (exec-masked)

    int l[KNN];
#pragma unroll
    for (int k = 0; k < KNN; ++k) l[k] = IMAX;

    if (sCov == 1)
        scan_batched<1>(W, st, cx, cy, cz, m2x, m2y, m2z, q2, qpos, wv, l);
    else
        scan_batched<2>(W, st, cx, cy, cz, m2x, m2y, m2z, q2, qpos, wv, l);

#pragma unroll
    for (int k = 0; k < KNN; ++k) mv[(wv * KNN + k) * QPB + lane] = l[k];
    __syncthreads();

    if (threadIdx.x < QPB) {                 // wave 0: lane == query
        int M[KNN];
#pragma unroll
        for (int k = 0; k < KNN; ++k) M[k] = IMAX;
#pragma unroll
        for (int e = 0; e < WPB; ++e) {
            int p[KNN];
#pragma unroll
            for (int k = 0; k < KNN; ++k) p[k] = mv[(e * KNN + k) * QPB + lane];
            merge_sorted(M, p);
        }

        const float tau = __int_as_float(M[KNN - 1] & MASK13);
        const float R = (float)sCov * H + df;
        const bool covered = (tau <= R * R * 0.996f);
        float v = 0.0f;
        if (covered) {
            float s1x = 0, s1y = 0, s1z = 0, s2x = 0, s2y = 0, s2z = 0;
#pragma unroll
            for (int k = 0; k < KNN; ++k) {
                const int j = M[k] & (NPTS - 1);
                const float4 c4 = W[j];
                const int oi = sI[j];
                s1x += c4.x; s1y += c4.y; s1z += c4.z;
                s2x += P2[3 * oi + 0];
                s2y += P2[3 * oi + 1];
                s2z += P2[3 * oi + 2];
            }
            const int oq = sI[qpos];
            const float p2x = P2[3 * oq + 0];
            const float p2y = P2[3 * oq + 1];
            const float p2z = P2[3 * oq + 2];
            const float dx = (s1x * 0.1f - qp.x) - (s2x * 0.1f - p2x);
            const float dy = (s1y * 0.1f - qp.y) - (s2y * 0.1f - p2y);
            const float dz = (s1z * 0.1f - qp.z) - (s2z * 0.1f - p2z);
            v = fabsf(dx) + fabsf(dy) + fabsf(dz);
        } else {
            const int wi = atomicAdd(nfail, 1);
            worklist[wi] = (batch << 16) | qpos;
        }
#pragma unroll
        for (int off = 32; off >= 1; off >>= 1) v += __shfl_down(v, off);
        if (threadIdx.x == 0)
            atomicAdd(out, v * (1.0f / (float)(NB * NPTS * 3)));
    }
}

// ---------------- phase 2: wave-per-query exact brute force (grid-wide) ----
constexpr int P2BLK = 256;
constexpr int P2GRID = 512;

__global__ __launch_bounds__(P2BLK)
void phase2(const float4* __restrict__ wsorted, const int* __restrict__ sIdx,
            const float* __restrict__ p2,
            const int* __restrict__ nfail, const int* __restrict__ worklist,
            float* __restrict__ out)
{
    const int lane = threadIdx.x & 63;
    const int wv   = threadIdx.x >> 6;
    const int wid  = blockIdx.x * (P2BLK / 64) + wv;
    const int NW   = P2GRID * (P2BLK / 64);
    const int nf   = *nfail;
    const int IMAX = 0x7FFFFFFF;
    float acc = 0.0f;

    for (int i = wid; i < nf; i += NW) {
        const int e = worklist[i];
        const int batch = e >> 16, qpos = e & 0xFFFF;
        const float4* W  = wsorted + batch * NPTS;
        const int*    sI = sIdx + batch * NPTS;
        const float*  P2 = p2 + (size_t)batch * NPTS * 3;
        const float4 qp = W[qpos];
        const float m2x = -2.0f * qp.x, m2y = -2.0f * qp.y, m2z = -2.0f * qp.z;
        const float q2 = qp.w;

        int l[KNN];
#pragma unroll
        for (int k = 0; k < KNN; ++k) l[k] = IMAX;

#pragma unroll 2
        for (int it = 0; it < NPTS / 128; ++it) {
            const int ja = it * 128 + lane, jb = ja + 64;
            const float4 ca = W[ja];
            const float4 cb = W[jb];
            const float da = fmaf(m2x, ca.x, fmaf(m2y, ca.y, fmaf(m2z, ca.z, ca.w + q2)));
            const float db = fmaf(m2x, cb.x, fmaf(m2y, cb.y, fmaf(m2z, cb.z, cb.w + q2)));
            int ka = (__float_as_int(da) & MASK13) | ja;
            int kb = (__float_as_int(db) & MASK13) | jb;
            ka = (ja == qpos) ? IMAX : ka;
            kb = (jb == qpos) ? IMAX : kb;
            ins2(l, ka, kb);
        }
        for (int off = 1; off < 64; off <<= 1) {
            int p[KNN];
#pragma unroll
            for (int k = 0; k < KNN; ++k) p[k] = __shfl_xor(l[k], off);
            merge_sorted(l, p);
        }
        float s1x = 0, s1y = 0, s1z = 0, s2x = 0, s2y = 0, s2z = 0;
#pragma unroll
        for (int k = 0; k < KNN; ++k) {
            const int j = l[k] & (NPTS - 1);
            const float4 c4 = W[j];
            const int oi = sI[j];
            s1x += c4.x; s1y += c4.y; s1z += c4.z;
            s2x += P2[3 * oi + 0];
            s2y += P2[3 * oi + 1];
            s2z += P2[3 * oi + 2];
        }
        const int oq = sI[qpos];
        const float dx = (s1x * 0.1f - qp.x) - (s2x * 0.1f - P2[3 * oq + 0]);
        const float dy = (s1y * 0.1f - qp.y) - (s2y * 0.1f - P2[3 * oq + 1]);
        const float dz = (s1z * 0.1f - qp.z) - (s2z * 0.1f - P2[3 * oq + 2]);
        if (lane == 0) acc += fabsf(dx) + fabsf(dy) + fabsf(dz);
    }

    if (lane == 0 && acc != 0.0f)
        atomicAdd(out, acc * (1.0f / (float)(NB * NPTS * 3)));
}

// ---------------- round-2 fallback (O(N^2), verified) ----------------
constexpr int FB_WPB = 8;
constexpr int FB_BLOCK = QPB * FB_WPB;  // 512
constexpr int CHUNK = NPTS / FB_WPB;

__global__ void prep_pack(const float* __restrict__ p, float4* __restrict__ w) {
    const int i = blockIdx.x * blockDim.x + threadIdx.x;
    if (i < NB * NPTS) {
        const float x = p[3 * i], y = p[3 * i + 1], z = p[3 * i + 2];
        w[i] = make_float4(x, y, z, fmaf(x, x, fmaf(y, y, z * z)));
    }
}

__global__ __launch_bounds__(FB_BLOCK, 2)
void knn_lap(const float4* __restrict__ w1, const float* __restrict__ p2,
             float* __restrict__ out)
{
    __shared__ int mv[FB_WPB * KNN * QPB];
    const int batch = blockIdx.x >> 7;
    const int qbase = (blockIdx.x & 127) << 6;
    const int lane  = threadIdx.x & 63;
    const int wv    = __builtin_amdgcn_readfirstlane(threadIdx.x >> 6);
    const int query = qbase + lane;
    const float4* Wb = w1 + batch * NPTS;
    const float4 qp = Wb[query];
    const float m2x = -2.0f * qp.x, m2y = -2.0f * qp.y, m2z = -2.0f * qp.z;
    const float q2 = qp.w;
    const int IMAX = 0x7FFFFFFF;
    int l[KNN];
#pragma unroll
    for (int k = 0; k < KNN; ++k) l[k] = IMAX;
    const int c0 = wv * CHUNK;
    const float4* cand = Wb + c0;
#pragma unroll 4
    for (int i = 0; i < CHUNK; i += 2) {
        const float4 ca = cand[i];
        const float4 cb = cand[i + 1];
        const int ja = c0 + i, jb = ja + 1;
        const float da = fmaf(m2x, ca.x, fmaf(m2y, ca.y, fmaf(m2z, ca.z, ca.w + q2)));
        const float db = fmaf(m2x, cb.x, fmaf(m2y, cb.y, fmaf(m2z, cb.z, cb.w + q2)));
        int ka = (__float_as_int(da) & MASK13) | ja;
        int kb = (__float_as_int(db) & MASK13) | jb;
        ka = (ja == query) ? IMAX : ka;
        kb = (jb == query) ? IMAX : kb;
        ins2(l, ka, kb);
    }
#pragma unroll
    for (int k = 0; k < KNN; ++k) mv[(wv * KNN + k) * QPB + lane] = l[k];
    __syncthreads();
    if (threadIdx.x < QPB) {
        int m[KNN];
#pragma unroll
        for (int k = 0; k < KNN; ++k) m[k] = IMAX;
#pragma unroll
        for (int e = 0; e < FB_WPB; ++e) {
            int p[KNN];
#pragma unroll
            for (int k = 0; k < KNN; ++k) p[k] = mv[(e * KNN + k) * QPB + lane];
            merge_sorted(m, p);
        }
        const float* P2b = p2 + (size_t)batch * NPTS * 3;
        float s1x = 0, s1y = 0, s1z = 0, s2x = 0, s2y = 0, s2z = 0;
#pragma unroll
        for (int k = 0; k < KNN; ++k) {
            const int j = m[k] & (NPTS - 1);
            const float4 c = Wb[j];
            s1x += c.x; s1y += c.y; s1z += c.z;
            s2x += P2b[3 * j + 0]; s2y += P2b[3 * j + 1]; s2z += P2b[3 * j + 2];
        }
        const int q = qbase + threadIdx.x;
        const float p2x = P2b[3 * q + 0], p2y = P2b[3 * q + 1], p2z = P2b[3 * q + 2];
        const float dx = (s1x * 0.1f - qp.x) - (s2x * 0.1f - p2x);
        const float dy = (s1y * 0.1f - qp.y) - (s2y * 0.1f - p2y);
        const float dz = (s1z * 0.1f - qp.z) - (s2z * 0.1f - p2z);
        float v = fabsf(dx) + fabsf(dy) + fabsf(dz);
#pragma unroll
        for (int off = 32; off >= 1; off >>= 1) v += __shfl_down(v, off);
        if (threadIdx.x == 0)
            atomicAdd(out, v * (1.0f / (float)(NB * NPTS * 3)));
    }
}

// ---------------- launcher ----------------
extern "C" void kernel_launch(void* const* d_in, const int* in_sizes, int n_in,
                              void* d_out, int out_size, void* d_ws, size_t ws_size,
                              hipStream_t stream) {
    const float* p1 = (const float*)d_in[0];
    const float* p2 = (const float*)d_in[1];
    float* out = (float*)d_out;

    size_t off = 0;
    float4* w       = (float4*)d_ws;                off += (size_t)NB * NPTS * 16;
    int*    hist    = (int*)((char*)d_ws + off);    off += (size_t)NB * NC * 4;
    int*    starts  = (int*)((char*)d_ws + off);    off += (size_t)NB * (NC + 1) * 4 + 8;
    int*    cellof  = (int*)((char*)d_ws + off);    off += (size_t)NB * NPTS * 4;
    float4* wsorted = (float4*)((char*)d_ws + off); off += (size_t)NB * NPTS * 16;
    int*    sIdx    = (int*)((char*)d_ws + off);    off += (size_t)NB * NPTS * 4;
    int*    nfail   = (int*)((char*)d_ws + off);    off += 16;
    int*    worklist= (int*)((char*)d_ws + off);    off += (size_t)NB * NPTS * 4;

    if (ws_size < off) {  // fallback: round-2 brute force
        hipMemsetAsync(out, 0, sizeof(float), stream);
        prep_pack<<<(NB * NPTS + 255) / 256, 256, 0, stream>>>(p1, w);
        knn_lap<<<NB * (NPTS / QPB), FB_BLOCK, 0, stream>>>(w, p2, out);
        return;
    }

    hipMemsetAsync(hist, 0, (size_t)NB * NC * 4, stream);
    pack_bin<<<(NB * NPTS + 255) / 256, 256, 0, stream>>>(p1, w, hist, cellof,
                                                          out, nfail);
    scan_cells<<<NB, 1024, 0, stream>>>(hist, starts);
    scatter_all<<<(NB * NPTS + 255) / 256, 256, 0, stream>>>(cellof, starts, hist,
                                                             w, wsorted, sIdx);
    phase1<<<NB * (NPTS / QPB), BLOCK, 0, stream>>>(wsorted, sIdx, p2, starts,
                                                    out, nfail, worklist);
    phase2<<<P2GRID, P2BLK, 0, stream>>>(wsorted, sIdx, p2, nfail, worklist, out);
}